// Round 8
// baseline (570.907 us; speedup 1.0000x reference)
//
#include <hip/hip_runtime.h>
#include <math.h>

// LCGLoss: B=256, L=512, D=512.
// S[(b,l),k] = (text @ C^T)[(b,l),k],  Cb[k][d] = bf16( (ip @ W_ML)[k][d] / tau )
// loss = mean over valid (i,l) of 0.5*(denom_log + logaddexp(s_iji, cross_log[i])) - s_iji

#define B_ 256
#define L_ 512
#define D_ 512
#define ROWS (B_ * L_)      // 131072
#define NT (ROWS / 64)      // 2048 row-tiles (M=64)
#define NEG_INF (-INFINITY)

typedef __attribute__((ext_vector_type(8))) short s8_t;     // 8 bf16 in 4 VGPRs
typedef __attribute__((ext_vector_type(4))) float f4_t;
typedef __attribute__((ext_vector_type(2))) float f2_t;
typedef __attribute__((ext_vector_type(4))) unsigned short us4_t;

__device__ inline unsigned short f2bf(float x) {
    unsigned int u = __float_as_uint(x);
    u += 0x7FFFu + ((u >> 16) & 1u);          // round-to-nearest-even
    return (unsigned short)(u >> 16);
}

typedef const __attribute__((address_space(1))) unsigned int as1_uint;
typedef __attribute__((address_space(3))) unsigned int as3_uint;
// async global->LDS, 16B per lane; LDS dest = wave-uniform base + lane*16
__device__ __attribute__((always_inline)) inline void gl_lds16(const void* g, void* l) {
    __builtin_amdgcn_global_load_lds((as1_uint*)g, (as3_uint*)l, 16, 0, 0);
}

// ---------------- Kcast: text f32 -> bf16 (one-time, memory-bound) ----------------
__global__ __launch_bounds__(256) void cast_kernel(const float* __restrict__ in,
                                                   unsigned short* __restrict__ out) {
    size_t i = ((size_t)blockIdx.x * 256 + threadIdx.x) * 8;
    f4_t a = *(const f4_t*)(in + i);
    f4_t b = *(const f4_t*)(in + i + 4);
    us4_t o0, o1;
    o0[0] = f2bf(a[0]); o0[1] = f2bf(a[1]); o0[2] = f2bf(a[2]); o0[3] = f2bf(a[3]);
    o1[0] = f2bf(b[0]); o1[1] = f2bf(b[1]); o1[2] = f2bf(b[2]); o1[3] = f2bf(b[3]);
    *(us4_t*)(out + i) = o0;
    *(us4_t*)(out + i + 4) = o1;
}

// ---------------- K0: ip[k][e] = sum_d img[k][d]*Wmv[e][d]; 32k x 64e tiles, 64 blocks ----
__global__ __launch_bounds__(256) void ip_kernel(const float* __restrict__ img,
                                                 const float* __restrict__ Wmv,
                                                 float* __restrict__ ip) {
    int kt = blockIdx.x >> 3, et = blockIdx.x & 7;
    __shared__ float Ast[32][36];
    __shared__ float Bst[32][72];
    int tid = threadIdx.x;
    int ty = tid >> 4;
    int tx = tid & 15;
    float acc[2][4] = {};
    int sr = tid >> 3, sc = (tid & 7) * 4;
    for (int d0 = 0; d0 < D_; d0 += 32) {
        f4_t a = *(const f4_t*)(img + (size_t)(kt * 32 + sr) * D_ + d0 + sc);
        f4_t b0 = *(const f4_t*)(Wmv + (size_t)(et * 64 + sr) * D_ + d0 + sc);
        f4_t b1 = *(const f4_t*)(Wmv + (size_t)(et * 64 + sr + 32) * D_ + d0 + sc);
        __syncthreads();
#pragma unroll
        for (int m = 0; m < 4; m++) {
            Ast[sc + m][sr] = a[m];
            Bst[sc + m][sr] = b0[m];
            Bst[sc + m][sr + 32] = b1[m];
        }
        __syncthreads();
#pragma unroll 4
        for (int d = 0; d < 32; d++) {
            f2_t a2 = *(const f2_t*)&Ast[d][ty * 2];
            f4_t b4 = *(const f4_t*)&Bst[d][tx * 4];
#pragma unroll
            for (int i = 0; i < 2; i++)
#pragma unroll
                for (int j = 0; j < 4; j++) acc[i][j] = fmaf(a2[i], b4[j], acc[i][j]);
        }
    }
#pragma unroll
    for (int i = 0; i < 2; i++) {
        f4_t o; o[0] = acc[i][0]; o[1] = acc[i][1]; o[2] = acc[i][2]; o[3] = acc[i][3];
        *(f4_t*)(ip + (size_t)(kt * 32 + ty * 2 + i) * D_ + et * 64 + tx * 4) = o;
    }
}

// ---------------- K1: Cb[k][d] = bf16( sum_e ip[k][e]*Wml[e][d] / tau ); 64 blocks -------
__global__ __launch_bounds__(256) void c_kernel(const float* __restrict__ ip,
                                                const float* __restrict__ Wml,
                                                const float* __restrict__ tau,
                                                unsigned short* __restrict__ Cb) {
    int kt = blockIdx.x >> 3, dt = blockIdx.x & 7;
    __shared__ float Ast[32][36];
    __shared__ float Bst[32][72];
    int tid = threadIdx.x;
    int ty = tid >> 4;
    int tx = tid & 15;
    float acc[2][4] = {};
    int sr = tid >> 3, sc = (tid & 7) * 4;
    int br = tid >> 4, bc = (tid & 15) * 4;
    for (int e0 = 0; e0 < D_; e0 += 32) {
        f4_t a = *(const f4_t*)(ip + (size_t)(kt * 32 + sr) * D_ + e0 + sc);
        f4_t b0 = *(const f4_t*)(Wml + (size_t)(e0 + br) * D_ + dt * 64 + bc);
        f4_t b1 = *(const f4_t*)(Wml + (size_t)(e0 + br + 16) * D_ + dt * 64 + bc);
        __syncthreads();
#pragma unroll
        for (int m = 0; m < 4; m++) Ast[sc + m][sr] = a[m];
        *(f4_t*)&Bst[br][bc] = b0;
        *(f4_t*)&Bst[br + 16][bc] = b1;
        __syncthreads();
#pragma unroll 4
        for (int e = 0; e < 32; e++) {
            f2_t a2 = *(const f2_t*)&Ast[e][ty * 2];
            f4_t b4 = *(const f4_t*)&Bst[e][tx * 4];
#pragma unroll
            for (int i = 0; i < 2; i++)
#pragma unroll
                for (int j = 0; j < 4; j++) acc[i][j] = fmaf(a2[i], b4[j], acc[i][j]);
        }
    }
    float it = 1.0f / fmaxf(tau[0], 0.001f);
#pragma unroll
    for (int i = 0; i < 2; i++) {
        us4_t o;
#pragma unroll
        for (int j = 0; j < 4; j++) o[j] = f2bf(acc[i][j] * it);
        *(us4_t*)(Cb + (size_t)(kt * 32 + ty * 2 + i) * D_ + dt * 64 + tx * 4) = o;
    }
}

// ---------------- Kmask: mbits[l*4+w] bit j = valid[w*64+j, l] ----------------
__global__ __launch_bounds__(256) void mask_kernel(const int* __restrict__ pad,
                                                   unsigned long long* __restrict__ mbits) {
    int l = blockIdx.x;
    int w = threadIdx.x >> 6;
    int j = threadIdx.x & 63;
    unsigned long long bal = __ballot(pad[(w * 64 + j) * L_ + l] == 0);
    if (j == 0) mbits[l * 4 + w] = bal;
}

// ======== shared epilogue (identical math in both gemm variants) ========
#define GEMM_EPILOGUE(Sh, pm, ps, rvadj)                                               \
    float cm = NEG_INF, cs = 0.f;                                                      \
    const int mw = bIdx >> 6, mb = bIdx & 63;                                          \
    _Pragma("unroll")                                                                  \
    for (int h = 0; h < 2; h++) {                                                      \
        __syncthreads();                                                               \
        _Pragma("unroll")                                                              \
        for (int mt2 = 0; mt2 < 2; mt2++) {                                            \
            int mt = h * 2 + mt2;                                                      \
            int rl = mt2 * 16 + qd * 4;                                                \
            _Pragma("unroll")                                                          \
            for (int nt = 0; nt < 4; nt++) {                                           \
                int col = wave * 64 + nt * 16 + mm;                                    \
                _Pragma("unroll")                                                      \
                for (int r = 0; r < 4; r++)                                            \
                    Sh[(rl + r) * 257 + col] = acc[mt][nt][r];                         \
            }                                                                          \
        }                                                                              \
        if (tid < 32) {                                                                \
            int l = l0 + h * 32 + tid;                                                 \
            rvadj[tid] = ((mbits[l * 4 + mw] >> mb) & 1ULL) ? 0.f : NEG_INF;           \
        }                                                                              \
        __syncthreads();                                                               \
        {                                                                              \
            float m2 = NEG_INF;                                                        \
            _Pragma("unroll 8")                                                        \
            for (int r = 0; r < 32; r++)                                               \
                m2 = fmaxf(m2, Sh[r * 257 + tid] + rvadj[r]);                          \
            if (m2 > NEG_INF) {                                                        \
                float s2 = 0.f;                                                        \
                _Pragma("unroll 8")                                                    \
                for (int r = 0; r < 32; r++)                                           \
                    s2 += __expf(Sh[r * 257 + tid] + rvadj[r] - m2);                   \
                float M = fmaxf(cm, m2);                                               \
                cs = cs * __expf(cm - M) + s2 * __expf(m2 - M);                        \
                cm = M;                                                                \
            }                                                                          \
        }                                                                              \
        if (tid < 128) {                                                               \
            int row = tid & 31, grp = tid >> 5;                                        \
            int l = l0 + h * 32 + row;                                                 \
            unsigned long long bits = mbits[l * 4 + grp];                              \
            const float* Srow = Sh + row * 257 + grp * 64;                             \
            float m = NEG_INF;                                                         \
            _Pragma("unroll 8")                                                        \
            for (int c = 0; c < 64; c++) {                                             \
                float adj = ((bits >> c) & 1ULL) ? 0.f : NEG_INF;                      \
                m = fmaxf(m, Srow[c] + adj);                                           \
            }                                                                          \
            float s = 0.f;                                                             \
            if (m > NEG_INF) {                                                         \
                _Pragma("unroll 8")                                                    \
                for (int c = 0; c < 64; c++) {                                         \
                    float adj = ((bits >> c) & 1ULL) ? 0.f : NEG_INF;                  \
                    s += __expf(Srow[c] + adj - m);                                    \
                }                                                                      \
            }                                                                          \
            pm[grp * 32 + row] = m;                                                    \
            ps[grp * 32 + row] = s;                                                    \
        }                                                                              \
        __syncthreads();                                                               \
        if (tid < 32) {                                                                \
            float m0 = pm[tid], m1 = pm[32 + tid], m2 = pm[64 + tid], m3 = pm[96 + tid];\
            float M = fmaxf(fmaxf(m0, m1), fmaxf(m2, m3));                             \
            float dl;                                                                  \
            if (M == NEG_INF) dl = NEG_INF;                                            \
            else {                                                                     \
                float s = ps[tid] * __expf(m0 - M) + ps[32 + tid] * __expf(m1 - M) +   \
                          ps[64 + tid] * __expf(m2 - M) + ps[96 + tid] * __expf(m3 - M);\
                dl = M + __logf(s);                                                    \
            }                                                                          \
            int gr = row0 + h * 32 + tid;                                              \
            denom[gr] = dl;                                                            \
            siji[gr] = Sh[tid * 257 + bIdx];                                           \
        }                                                                              \
    }                                                                                  \
    if (tid == bIdx) { cm = NEG_INF; cs = 0.f; }                                       \
    crossM[(size_t)tid * NT + tile] = cm;                                              \
    crossS[(size_t)tid * NT + tile] = cs;

// ---------------- K2: pure-bf16 MFMA GEMM, M=64 x N=256, BK=64, all global_load_lds ------
// A layout: byte      (row*8 + (j ^ (row&7)))*16,  row 0..63,  j 0..7 (8 bf16 per chunk)
// B layout: byte 8192+(col*8 + (j ^ (col&7)))*16,  col 0..255, j 0..7
__global__ __launch_bounds__(256) void gemm_bf16_kernel(
    const unsigned short* __restrict__ At, const unsigned short* __restrict__ Cb,
    const unsigned long long* __restrict__ mbits,
    float* __restrict__ denom, float* __restrict__ siji,
    float* __restrict__ crossM, float* __restrict__ crossS) {
    // 40 KB LDS: staging A [0,8192) B [8192,40960); epilogue overlay 8512 floats
    __shared__ __align__(16) float lds[10240];
    float* Sh  = lds;
    float* pm  = lds + 8224;
    float* ps  = lds + 8352;
    float* rvadj = lds + 8480;

    const int tile = blockIdx.x;
    const int row0 = tile * 64;
    const int bIdx = row0 >> 9;
    const int l0 = row0 & 511;
    const int tid = threadIdx.x;
    const int wave = tid >> 6;
    const int lane = tid & 63;
    const int qd = lane >> 4;
    const int mm = lane & 15;

    f4_t acc[4][4];
#pragma unroll
    for (int mt = 0; mt < 4; mt++)
#pragma unroll
        for (int nt = 0; nt < 4; nt++)
#pragma unroll
            for (int r = 0; r < 4; r++) acc[mt][nt][r] = 0.f;

    char* ldsc = (char*)lds;

#pragma unroll 1
    for (int k0 = 0; k0 < D_; k0 += 64) {
        __syncthreads();               // prev compute done reading LDS
        // A: 512 chunks of 16B (64 rows x 8), 2 instrs x 256 threads
#pragma unroll
        for (int i = 0; i < 2; i++) {
            int c = i * 256 + tid;
            int row = c >> 3, j = c & 7;
            int jg = j ^ (row & 7);
            const unsigned short* g = At + (size_t)(row0 + row) * D_ + k0 + jg * 8;
            gl_lds16(g, ldsc + (i * 256 + wave * 64) * 16);
        }
        // B: 2048 chunks of 16B (256 cols x 8), 8 instrs x 256 threads
#pragma unroll
        for (int i = 0; i < 8; i++) {
            int c = i * 256 + tid;
            int col = c >> 3, j = c & 7;
            int jg = j ^ (col & 7);
            const unsigned short* g = Cb + (size_t)col * D_ + k0 + jg * 8;
            gl_lds16(g, ldsc + 8192 + (i * 256 + wave * 64) * 16);
        }
        __syncthreads();               // vmcnt(0) drain -> LDS visible
#pragma unroll
        for (int s = 0; s < 2; s++) {  // two K=32 MFMA sub-steps
            s8_t af[4], bfr[4];
            int jj = (s * 4 + qd) ^ (mm & 7);
#pragma unroll
            for (int mt = 0; mt < 4; mt++) {
                int row = mt * 16 + mm;
                af[mt] = *(const s8_t*)(ldsc + row * 128 + jj * 16);
            }
#pragma unroll
            for (int nt = 0; nt < 4; nt++) {
                int col = wave * 64 + nt * 16 + mm;
                bfr[nt] = *(const s8_t*)(ldsc + 8192 + col * 128 + jj * 16);
            }
#pragma unroll
            for (int mt = 0; mt < 4; mt++)
#pragma unroll
                for (int nt = 0; nt < 4; nt++)
                    acc[mt][nt] = __builtin_amdgcn_mfma_f32_16x16x32_bf16(
                        af[mt], bfr[nt], acc[mt][nt], 0, 0, 0);
        }
    }

    // NOTE: epilogue h-loop fully unrolled (macro) — runtime acc index spills (R3).
    GEMM_EPILOGUE(Sh, pm, ps, rvadj)
}

// ---------------- K2-fallback (R7): f32-A variant, used when ws too small ----------------
__global__ __launch_bounds__(256) void gemm_mfma_kernel(
    const float* __restrict__ text, const unsigned short* __restrict__ Cb,
    const unsigned long long* __restrict__ mbits,
    float* __restrict__ denom, float* __restrict__ siji,
    float* __restrict__ crossM, float* __restrict__ crossS) {
    __shared__ __align__(16) float lds[12288];
    float* Sh  = lds;
    float* pm  = lds + 8224;
    float* ps  = lds + 8352;
    float* rvadj = lds + 8480;

    const int tile = blockIdx.x;
    const int row0 = tile * 64;
    const int bIdx = row0 >> 9;
    const int l0 = row0 & 511;
    const int tid = threadIdx.x;
    const int wave = tid >> 6;
    const int lane = tid & 63;
    const int qd = lane >> 4;
    const int mm = lane & 15;

    f4_t acc[4][4];
#pragma unroll
    for (int mt = 0; mt < 4; mt++)
#pragma unroll
        for (int nt = 0; nt < 4; nt++)
#pragma unroll
            for (int r = 0; r < 4; r++) acc[mt][nt][r] = 0.f;

    char* ldsc = (char*)lds;

#pragma unroll 1
    for (int k0 = 0; k0 < D_; k0 += 64) {
        __syncthreads();
#pragma unroll
        for (int i = 0; i < 4; i++) {
            int c = i * 256 + tid;
            int row = c >> 4, j = c & 15;
            int jg = j ^ ((row & 7) << 1);
            const float* g = text + (size_t)(row0 + row) * D_ + k0 + jg * 4;
            gl_lds16(g, ldsc + (i * 256 + wave * 64) * 16);
        }
#pragma unroll
        for (int i = 0; i < 8; i++) {
            int c = i * 256 + tid;
            int col = c >> 3, j = c & 7;
            int jg = j ^ (col & 7);
            const unsigned short* g = Cb + (size_t)col * D_ + k0 + jg * 8;
            gl_lds16(g, ldsc + 16384 + (i * 256 + wave * 64) * 16);
        }
        __syncthreads();
#pragma unroll
        for (int s = 0; s < 2; s++) {
            s8_t af[4], bfr[4];
#pragma unroll
            for (int mt = 0; mt < 4; mt++) {
                int row = mt * 16 + mm;
                int j0 = (s * 8 + qd * 2) ^ ((mm & 7) << 1);
                const f4_t* ap = (const f4_t*)(ldsc + row * 256 + j0 * 16);
                f4_t x0 = ap[0], x1 = ap[1];
                s8_t h;
                h[0] = (short)f2bf(x0[0]); h[1] = (short)f2bf(x0[1]);
                h[2] = (short)f2bf(x0[2]); h[3] = (short)f2bf(x0[3]);
                h[4] = (short)f2bf(x1[0]); h[5] = (short)f2bf(x1[1]);
                h[6] = (short)f2bf(x1[2]); h[7] = (short)f2bf(x1[3]);
                af[mt] = h;
            }
#pragma unroll
            for (int nt = 0; nt < 4; nt++) {
                int col = wave * 64 + nt * 16 + mm;
                int j = (s * 4 + qd) ^ (mm & 7);
                bfr[nt] = *(const s8_t*)(ldsc + 16384 + col * 128 + j * 16);
            }
#pragma unroll
            for (int mt = 0; mt < 4; mt++)
#pragma unroll
                for (int nt = 0; nt < 4; nt++)
                    acc[mt][nt] = __builtin_amdgcn_mfma_f32_16x16x32_bf16(
                        af[mt], bfr[nt], acc[mt][nt], 0, 0, 0);
        }
    }
    GEMM_EPILOGUE(Sh, pm, ps, rvadj)
}

// ---------------- K3: cross_log[i] = merge of 2048 (m,s) partials ----------------
__global__ __launch_bounds__(256) void cross_combine_kernel(const float* __restrict__ crossM,
                                                            const float* __restrict__ crossS,
                                                            float* __restrict__ crossLog) {
    int i = blockIdx.x;
    int tid = threadIdx.x;
    float m = NEG_INF, s = 0.f;
    for (int e = 0; e < NT / 256; e++) {
        int t = e * 256 + tid;
        float m2 = crossM[(size_t)i * NT + t];
        float s2 = crossS[(size_t)i * NT + t];
        if (m2 > NEG_INF) {
            if (m == NEG_INF) { m = m2; s = s2; }
            else {
                float M = fmaxf(m, m2);
                s = s * expf(m - M) + s2 * expf(m2 - M);
                m = M;
            }
        }
    }
    __shared__ float sm[256], ss[256];
    sm[tid] = m; ss[tid] = s;
    __syncthreads();
    for (int off = 128; off > 0; off >>= 1) {
        if (tid < off) {
            float m1 = sm[tid], s1 = ss[tid];
            float m2 = sm[tid + off], s2 = ss[tid + off];
            float M = fmaxf(m1, m2);
            float sv;
            if (M == NEG_INF) sv = 0.f;
            else sv = s1 * expf(m1 - M) + s2 * expf(m2 - M);
            sm[tid] = M; ss[tid] = sv;
        }
        __syncthreads();
    }
    if (tid == 0) crossLog[i] = (sm[0] == NEG_INF) ? NEG_INF : sm[0] + logf(ss[0]);
}

// ---------------- K4: per-block partial loss sums ----------------
__global__ __launch_bounds__(256) void loss_partial_kernel(
    const int* __restrict__ pad, const float* __restrict__ denom,
    const float* __restrict__ siji, const float* __restrict__ crossLog,
    float* __restrict__ psum, float* __restrict__ pcnt) {
    int tid = threadIdx.x;
    int idx = blockIdx.x * 256 + tid;
    float term = 0.f, cnt = 0.f;
    if (pad[idx] == 0) {
        float dl = denom[idx], sv = siji[idx], cl = crossLog[idx >> 9];
        float M = fmaxf(sv, cl);
        float neg = M + log1pf(expf(-fabsf(sv - cl)));
        term = 0.5f * (dl + neg) - sv;
        cnt = 1.f;
    }
    __shared__ float bs[256], bc[256];
    bs[tid] = term; bc[tid] = cnt;
    __syncthreads();
    for (int off = 128; off > 0; off >>= 1) {
        if (tid < off) { bs[tid] += bs[tid + off]; bc[tid] += bc[tid + off]; }
        __syncthreads();
    }
    if (tid == 0) { psum[blockIdx.x] = bs[0]; pcnt[blockIdx.x] = bc[0]; }
}

// ---------------- K5: final reduce of 512 partials ----------------
__global__ __launch_bounds__(256) void final_kernel(const float* __restrict__ psum,
                                                    const float* __restrict__ pcnt,
                                                    float* __restrict__ out) {
    int tid = threadIdx.x;
    __shared__ float bs[256], bc[256];
    bs[tid] = psum[tid] + psum[tid + 256];
    bc[tid] = pcnt[tid] + pcnt[tid + 256];
    __syncthreads();
    for (int off = 128; off > 0; off >>= 1) {
        if (tid < off) { bs[tid] += bs[tid + off]; bc[tid] += bc[tid + off]; }
        __syncthreads();
    }
    if (tid == 0) out[0] = bs[0] / bc[0];
}

extern "C" void kernel_launch(void* const* d_in, const int* in_sizes, int n_in,
                              void* d_out, int out_size, void* d_ws, size_t ws_size,
                              hipStream_t stream) {
    (void)in_sizes; (void)n_in; (void)out_size;
    const float* text = (const float*)d_in[0];
    const float* img  = (const float*)d_in[1];
    const float* Wml  = (const float*)d_in[2];
    const float* Wmv  = (const float*)d_in[3];
    const float* tau  = (const float*)d_in[4];
    const int* pad    = (const int*)d_in[5];
    float* out = (float*)d_out;

    float* ws = (float*)d_ws;
    float* ip       = ws;                      // 131072 fl
    unsigned short* Cb = (unsigned short*)(ws + 131072);  // 131072 ushort
    unsigned long long* mbits = (unsigned long long*)(ws + 262144); // 2048 u64
    float* denom    = ws + 266240;             // 131072
    float* siji     = ws + 397312;             // 131072
    float* crossM   = ws + 528384;             // 524288 (256 x 2048)
    float* crossS   = ws + 1052672;            // 524288
    float* crossLog = ws + 1576960;            // 256
    float* psum     = ws + 1577216;            // 512
    float* pcnt     = ws + 1577728;            // 512
    unsigned short* textbf = (unsigned short*)(ws + 1578240);  // ROWS*D_ bf16 = 134 MB
    size_t need = 1578240ull * 4 + (size_t)ROWS * D_ * 2;

    hipLaunchKernelGGL(ip_kernel,   dim3(64),  dim3(256), 0, stream, img, Wmv, ip);
    hipLaunchKernelGGL(c_kernel,    dim3(64),  dim3(256), 0, stream, ip, Wml, tau, Cb);
    hipLaunchKernelGGL(mask_kernel, dim3(L_),  dim3(256), 0, stream, pad, mbits);
    if (ws_size >= need) {
        hipLaunchKernelGGL(cast_kernel, dim3((ROWS * D_) / (256 * 8)), dim3(256), 0, stream,
                           text, textbf);
        hipLaunchKernelGGL(gemm_bf16_kernel, dim3(NT), dim3(256), 0, stream,
                           textbf, Cb, mbits, denom, siji, crossM, crossS);
    } else {
        hipLaunchKernelGGL(gemm_mfma_kernel, dim3(NT), dim3(256), 0, stream,
                           text, Cb, mbits, denom, siji, crossM, crossS);
    }
    hipLaunchKernelGGL(cross_combine_kernel, dim3(B_), dim3(256), 0, stream,
                       crossM, crossS, crossLog);
    hipLaunchKernelGGL(loss_partial_kernel, dim3(ROWS / 256), dim3(256), 0, stream,
                       pad, denom, siji, crossLog, psum, pcnt);
    hipLaunchKernelGGL(final_kernel, dim3(1), dim3(256), 0, stream, psum, pcnt, out);
}